// Round 10
// baseline (496.142 us; speedup 1.0000x reference)
//
#include <hip/hip_runtime.h>
#include <cstdint>

typedef _Float16 f16;
typedef uint32_t u32;
typedef f16 f16x2 __attribute__((ext_vector_type(2)));
typedef f16 f16x8 __attribute__((ext_vector_type(8)));
typedef float f32x4 __attribute__((ext_vector_type(4)));
typedef u32 u32x4 __attribute__((ext_vector_type(4)));

#define NROWS 32768   // B*S = 8*4096
#define D_IN 1024
#define M_DIM 512
#define NKEYS 4096
#define KTOP 8

__device__ __forceinline__ u32 umax32(u32 a, u32 b) { return a > b ? a : b; }
__device__ __forceinline__ u32 umin32(u32 a, u32 b) { return a < b ? a : b; }

// async global->LDS, 16B per lane. LDS dest is wave-uniform base + lane*16 (HW).
__device__ __forceinline__ void gload_lds16(const void* src, void* dst) {
  __builtin_amdgcn_global_load_lds(
      (const __attribute__((address_space(1))) uint32_t*)src,
      (__attribute__((address_space(3))) uint32_t*)dst, 16, 0, 0);
}

// ---------------------------------------------------------------------------
// prep: fp32->fp16 conversions + weight transposes (LDS-tiled, coalesced)
// ---------------------------------------------------------------------------
__global__ void prep_kernel(const float* __restrict__ keys, const float* __restrict__ values,
                            const float* __restrict__ wq, const float* __restrict__ wo,
                            f16* __restrict__ keys_h, f16* __restrict__ values_h,
                            f16* __restrict__ wqT, f16* __restrict__ woT) {
  const int b = blockIdx.x, t = threadIdx.x;
  if (b < 2048) {
    const float* src = (b < 1024) ? keys : values;
    f16* dst = (b < 1024) ? keys_h : values_h;
    const int bb = b & 1023;
    const size_t base = (size_t)bb * 2048 + (size_t)t * 8;
    f32x4 a = *(const f32x4*)(src + base);
    f32x4 c2 = *(const f32x4*)(src + base + 4);
    f16x8 o;
    o[0] = (f16)a[0]; o[1] = (f16)a[1]; o[2] = (f16)a[2]; o[3] = (f16)a[3];
    o[4] = (f16)c2[0]; o[5] = (f16)c2[1]; o[6] = (f16)c2[2]; o[7] = (f16)c2[3];
    *(f16x8*)(dst + base) = o;
    return;
  }
  __shared__ float lds[64][65];
  if (b < 2176) {
    // wq: [1024 d][512 m] -> wqT [512 m][1024 d]
    const int tb = b - 2048;           // 0..127
    const int td = tb >> 3, tm = tb & 7;
#pragma unroll
    for (int p = 0; p < 16; ++p) {
      const int d_loc = p * 4 + (t >> 6), m_loc = t & 63;
      lds[d_loc][m_loc] = wq[(size_t)(td * 64 + d_loc) * 512 + tm * 64 + m_loc];
    }
    __syncthreads();
#pragma unroll
    for (int p = 0; p < 16; ++p) {
      const int m_loc = p * 4 + (t >> 6), d_loc = t & 63;
      wqT[(size_t)(tm * 64 + m_loc) * 1024 + td * 64 + d_loc] = (f16)lds[d_loc][m_loc];
    }
  } else {
    // wo: [512 m][1024 od] -> woT [1024 od][512 m]
    const int tb = b - 2176;           // 0..127
    const int tmm = tb >> 4, tod = tb & 15;
#pragma unroll
    for (int p = 0; p < 16; ++p) {
      const int m_loc = p * 4 + (t >> 6), od_loc = t & 63;
      lds[m_loc][od_loc] = wo[(size_t)(tmm * 64 + m_loc) * 1024 + tod * 64 + od_loc];
    }
    __syncthreads();
#pragma unroll
    for (int p = 0; p < 16; ++p) {
      const int od_loc = p * 4 + (t >> 6), m_loc = t & 63;
      woT[(size_t)(tod * 64 + od_loc) * 512 + tmm * 64 + m_loc] = (f16)lds[m_loc][od_loc];
    }
  }
}

// ---------------------------------------------------------------------------
// qproj (r2 version, proven): row-major LDS + XOR swizzle, coalesced staging.
// ---------------------------------------------------------------------------
__global__ __launch_bounds__(256, 2) void qproj_kernel(
    const float* __restrict__ query, const f16* __restrict__ wqT,
    const float* __restrict__ bq, f16* __restrict__ q_out) {
  __shared__ f16 Atile[32 * 1024];   // 64 KB
  const int tid = threadIdx.x;
  const int wave = tid >> 6, lane = tid & 63;
  const int g = lane >> 4, c = lane & 15;
  const int rowbase = blockIdx.x * 64 + wave * 16;
  const int row = rowbase + c;

  f16x8 Breg[32];
  {
    const float* qrow = query + (size_t)row * D_IN;
#pragma unroll
    for (int kk = 0; kk < 32; ++kk) {
      f32x4 lo = *(const f32x4*)(qrow + kk * 32 + g * 8);
      f32x4 hi = *(const f32x4*)(qrow + kk * 32 + g * 8 + 4);
      f16x8 v;
      v[0] = (f16)lo[0]; v[1] = (f16)lo[1]; v[2] = (f16)lo[2]; v[3] = (f16)lo[3];
      v[4] = (f16)hi[0]; v[5] = (f16)hi[1]; v[6] = (f16)hi[2]; v[7] = (f16)hi[3];
      Breg[kk] = v;
    }
  }

  for (int mt = 0; mt < 16; ++mt) {
    __syncthreads();
#pragma unroll
    for (int i2 = 0; i2 < 8; ++i2) {
      const int kr = wave * 8 + i2;
#pragma unroll
      for (int hb = 0; hb < 2; ++hb) {
        const u32 slot = (u32)(hb * 1024 + lane * 16);
        const u32 kb = slot ^ (u32)((kr & 7) << 4);
        const char* src = (const char*)(wqT + (size_t)(mt * 32 + kr) * D_IN) + kb;
        gload_lds16(src, (char*)Atile + kr * 2048 + hb * 1024);
      }
    }
    asm volatile("s_waitcnt vmcnt(0)" ::: "memory");
    __syncthreads();

    f32x4 acc0 = {0.f, 0.f, 0.f, 0.f};
    f32x4 acc1 = {0.f, 0.f, 0.f, 0.f};
#pragma unroll
    for (int kk = 0; kk < 32; ++kk) {
      const u32 base = (u32)(kk * 64 + g * 16);
      {
        const int ml = c;
        const u32 off = (u32)(ml * 2048) + (base ^ (u32)((ml & 7) << 4));
        f16x8 a = *(const f16x8*)((const char*)Atile + off);
        acc0 = __builtin_amdgcn_mfma_f32_16x16x32_f16(a, Breg[kk], acc0, 0, 0, 0);
      }
      {
        const int ml = 16 + c;
        const u32 off = (u32)(ml * 2048) + (base ^ (u32)((ml & 7) << 4));
        f16x8 a = *(const f16x8*)((const char*)Atile + off);
        acc1 = __builtin_amdgcn_mfma_f32_16x16x32_f16(a, Breg[kk], acc1, 0, 0, 0);
      }
    }

    f32x4 bq0 = *(const f32x4*)(bq + mt * 32 + g * 4);
    f32x4 bq1 = *(const f32x4*)(bq + mt * 32 + 16 + g * 4);
    f16* qp = q_out + (size_t)row * M_DIM + mt * 32 + g * 4;
    f16x2 p;
    p[0] = (f16)(acc0[0] + bq0[0]); p[1] = (f16)(acc0[1] + bq0[1]); *(f16x2*)(qp + 0) = p;
    p[0] = (f16)(acc0[2] + bq0[2]); p[1] = (f16)(acc0[3] + bq0[3]); *(f16x2*)(qp + 2) = p;
    p[0] = (f16)(acc1[0] + bq1[0]); p[1] = (f16)(acc1[1] + bq1[1]); *(f16x2*)(qp + 16) = p;
    p[0] = (f16)(acc1[2] + bq1[2]); p[1] = (f16)(acc1[3] + bq1[3]); *(f16x2*)(qp + 18) = p;
  }
}

// ---------------------------------------------------------------------------
// scores+topk over a HALF of the key range (2048 keys), 16x16x32 MFMA,
// 512-thread blocks, 4 waves/SIMD (r7 base, fragment-major LDS, 0 conflicts)
// + HYBRID OPERAND FEED: per tile-wave, 24 A-fragments from LDS (slices
// 0..23) and 8 directly from global (keys are L2-resident; VMEM pipe was
// idle while LDS pipe was the 88%-busy wall). LDS read floor drops 164->123
// us. Identical operand values + per-acc accumulation order (acc1: kk 0-7
// LDS, kk 8-15 regs) -> bit-identical output to r7/r9.
// ---------------------------------------------------------------------------
__global__ __launch_bounds__(512, 4) void scores_topk_kernel(
    const f16* __restrict__ q, const f16* __restrict__ keys_h,
    u32* __restrict__ cand) {
  __shared__ f16 Ktile[2 * 24 * 512];   // 48 KB: 2 buf x 24 slices x 1KB
  const int tid = threadIdx.x;
  const int wave = tid >> 6, lane = tid & 63;
  const int g = lane >> 4, c = lane & 15;
  const int rb = blockIdx.x >> 1, half = blockIdx.x & 1;
  const int rowbase = rb * 128 + wave * 16;
  const int myrow = rowbase + c;
  const int keybase = half * 2048;

  f16x8 Breg[16];
  {
    const f16* qr = q + (size_t)myrow * M_DIM;
#pragma unroll
    for (int kk = 0; kk < 16; ++kk)
      Breg[kk] = *(const f16x8*)(qr + kk * 32 + g * 8);
  }

  u32 top[KTOP];
#pragma unroll
  for (int j = 0; j < KTOP; ++j) top[j] = 0u;

  // slices 0..15: keys [kt*32,+16) dims s*32;  16..23: keys [kt*32+16,+16) dims (s-16)*32
  const int laneoff = c * M_DIM + g * 8;
  auto stage = [&](int buf, int kt) {
    const f16* base = keys_h + (size_t)(keybase + kt * 32) * M_DIM + laneoff;
    char* dbase = (char*)Ktile + buf * 24576;
#pragma unroll
    for (int i2 = 0; i2 < 3; ++i2) {
      const int s = wave * 3 + i2;
      const int srow = (s < 16) ? 0 : 16;
      const int sdim = (s < 16) ? (s * 32) : ((s - 16) * 32);
      gload_lds16(base + srow * M_DIM + sdim, dbase + s * 1024);
    }
  };

  // direct-global fragment pointer (keys L2-resident): lane (g,c) consumes
  // keys[kt*32+16+c][kk*32 + g*8 ..] for kk = 8..15
  const f16* gp0 = keys_h + (size_t)(keybase + 16 + c) * M_DIM + g * 8;

  stage(0, 0);
  asm volatile("s_waitcnt vmcnt(0)" ::: "memory");
  __syncthreads();

  const char* base_rd = (const char*)Ktile + lane * 16;

  for (int kt = 0; kt < 64; ++kt) {
    const int cur = kt & 1;

    // issue the 8 direct loads first (needed mid-tile), then next-tile staging
    f16x8 grg[8];
    {
      const f16* gp = gp0 + (size_t)kt * 32 * M_DIM;
#pragma unroll
      for (int j = 0; j < 8; ++j)
        grg[j] = *(const f16x8*)(gp + (8 + j) * 32);
    }
    if (kt < 63) stage(cur ^ 1, kt + 1);

    f32x4 acc0 = {0.f, 0.f, 0.f, 0.f};
    f32x4 acc1 = {0.f, 0.f, 0.f, 0.f};
    const char* tb = base_rd + cur * 24576;
    __builtin_amdgcn_s_setprio(1);
#pragma unroll
    for (int kk = 0; kk < 16; ++kk) {
      f16x8 a0 = *(const f16x8*)(tb + kk * 1024);           // keys kt*32+c
      acc0 = __builtin_amdgcn_mfma_f32_16x16x32_f16(a0, Breg[kk], acc0, 0, 0, 0);
    }
#pragma unroll
    for (int kk = 0; kk < 8; ++kk) {
      f16x8 a1 = *(const f16x8*)(tb + (16 + kk) * 1024);    // keys kt*32+16+c, dims kk*32
      acc1 = __builtin_amdgcn_mfma_f32_16x16x32_f16(a1, Breg[kk], acc1, 0, 0, 0);
    }
#pragma unroll
    for (int kk = 8; kk < 16; ++kk) {
      acc1 = __builtin_amdgcn_mfma_f32_16x16x32_f16(grg[kk - 8], Breg[kk], acc1, 0, 0, 0);
    }
    __builtin_amdgcn_s_setprio(0);

#pragma unroll
    for (int i = 0; i < 4; ++i) {
      {
        const float s = acc0[i];
        const u32 kidx = (u32)(keybase + kt * 32 + g * 4 + i);
        const int bi = __float_as_int(s);
        const u32 mono = (u32)bi ^ (u32)((bi >> 31) | 0x80000000);   // order-preserving
        u32 x = ((mono + 0x800u) & 0xFFFFF000u) | kidx;              // 20b score + 12b idx
#pragma unroll
        for (int j = 0; j < KTOP; ++j) { const u32 nt = umax32(top[j], x); x = umin32(top[j], x); top[j] = nt; }
      }
      {
        const float s = acc1[i];
        const u32 kidx = (u32)(keybase + kt * 32 + 16 + g * 4 + i);
        const int bi = __float_as_int(s);
        const u32 mono = (u32)bi ^ (u32)((bi >> 31) | 0x80000000);
        u32 x = ((mono + 0x800u) & 0xFFFFF000u) | kidx;
#pragma unroll
        for (int j = 0; j < KTOP; ++j) { const u32 nt = umax32(top[j], x); x = umin32(top[j], x); top[j] = nt; }
      }
    }

    asm volatile("s_waitcnt vmcnt(0)" ::: "memory");
    __syncthreads();
  }

  // merge across the 4 g-lanes sharing row c (disjoint key subsets -> exact)
#pragma unroll
  for (int st = 16; st <= 32; st <<= 1) {
    u32 oth[KTOP];
#pragma unroll
    for (int j = 0; j < KTOP; ++j) oth[j] = (u32)__shfl((int)top[j], lane ^ st);
#pragma unroll
    for (int j = 0; j < KTOP; ++j) {
      u32 x = oth[j];
#pragma unroll
      for (int jj = 0; jj < KTOP; ++jj) { const u32 nt = umax32(top[jj], x); x = umin32(top[jj], x); top[jj] = nt; }
    }
  }

  if (g == 0) {
    u32* cp = cand + (size_t)myrow * 16 + half * 8;
    u32x4 a, b;
    a.x = top[0]; a.y = top[1]; a.z = top[2]; a.w = top[3];
    b.x = top[4]; b.y = top[5]; b.z = top[6]; b.w = top[7];
    *(u32x4*)(cp) = a;
    *(u32x4*)(cp + 4) = b;
  }
}

// ---------------------------------------------------------------------------
// merge halves + softmax + gather. (unchanged)
// ---------------------------------------------------------------------------
__global__ __launch_bounds__(256, 4) void merge_gather_kernel(
    const u32* __restrict__ cand, const f16* __restrict__ values_h,
    f16* __restrict__ mem_out) {
  const int tid = threadIdx.x;
  const int wave = tid >> 6, lane = tid & 63;
  const int rowbase = blockIdx.x * 32 + wave * 8;
  const int myrow = rowbase + (lane & 7);

  const u32* cp = cand + (size_t)myrow * 16;
  u32x4 a0 = *(const u32x4*)(cp);
  u32x4 a1 = *(const u32x4*)(cp + 4);
  u32x4 b0 = *(const u32x4*)(cp + 8);
  u32x4 b1 = *(const u32x4*)(cp + 12);
  u32 top[KTOP] = {a0.x, a0.y, a0.z, a0.w, a1.x, a1.y, a1.z, a1.w};
  u32 ins[KTOP] = {b0.x, b0.y, b0.z, b0.w, b1.x, b1.y, b1.z, b1.w};
#pragma unroll
  for (int j = 0; j < KTOP; ++j) {
    u32 x = ins[j];
#pragma unroll
    for (int jj = 0; jj < KTOP; ++jj) { const u32 nt = umax32(top[jj], x); x = umin32(top[jj], x); top[jj] = nt; }
  }

  float w[KTOP]; u32 idx[KTOP];
  {
    float s[KTOP];
#pragma unroll
    for (int j = 0; j < KTOP; ++j) {
      const u32 mono = top[j] & 0xFFFFF000u;
      const u32 bits = (mono & 0x80000000u) ? (mono ^ 0x80000000u) : ~mono;
      s[j] = __int_as_float(bits);
      idx[j] = top[j] & 0xFFFu;
    }
    const float m0 = s[0];
    float sum = 0.f;
#pragma unroll
    for (int j = 0; j < KTOP; ++j) { w[j] = __expf(s[j] - m0); sum += w[j]; }
    const float inv = 1.f / sum;
#pragma unroll
    for (int j = 0; j < KTOP; ++j) w[j] *= inv;
  }

  for (int r = 0; r < 8; ++r) {
    float acc2[8];
#pragma unroll
    for (int e = 0; e < 8; ++e) acc2[e] = 0.f;
#pragma unroll
    for (int j = 0; j < KTOP; ++j) {
      const u32 ix = (u32)__shfl((int)idx[j], r);
      const float wj = __shfl(w[j], r);
      const f16x8 v = *(const f16x8*)(values_h + (size_t)ix * M_DIM + lane * 8);
#pragma unroll
      for (int e = 0; e < 8; ++e) acc2[e] += wj * (float)v[e];
    }
    f16x8 o;
#pragma unroll
    for (int e = 0; e < 8; ++e) o[e] = (f16)acc2[e];
    *(f16x8*)(mem_out + (size_t)(rowbase + r) * M_DIM + lane * 8) = o;
  }
}

// ---------------------------------------------------------------------------
// outproj (r9 version): r2 math + mt-loop split across grid (4 blocks/CU).
// ---------------------------------------------------------------------------
__global__ __launch_bounds__(256, 4) void outproj_kernel(
    const f16* __restrict__ mem_h, const f16* __restrict__ woT,
    const float* __restrict__ bo, const float* __restrict__ query,
    float* __restrict__ out) {
  __shared__ f16 Atile[32 * 512];   // 32 KB
  const int tid = threadIdx.x;
  const int wave = tid >> 6, lane = tid & 63;
  const int g = lane >> 4, c = lane & 15;
  const int rbk = blockIdx.x >> 1, mh = blockIdx.x & 1;
  const int rowbase = rbk * 64 + wave * 16;
  const int row = rowbase + c;

  f16x8 Breg[16];
  {
    const f16* mr = mem_h + (size_t)row * M_DIM;
#pragma unroll
    for (int kk = 0; kk < 16; ++kk)
      Breg[kk] = *(const f16x8*)(mr + kk * 32 + g * 8);
  }

  for (int mt = mh * 16; mt < mh * 16 + 16; ++mt) {
    __syncthreads();
#pragma unroll
    for (int i2 = 0; i2 < 8; ++i2) {
      const int kr = wave * 8 + i2;
      const u32 kb = ((u32)(lane * 16)) ^ ((u32)((kr & 7) << 4));
      const char* src = (const char*)(woT + (size_t)(mt * 32 + kr) * M_DIM) + kb;
      gload_lds16(src, (char*)Atile + kr * 1024);
    }
    asm volatile("s_waitcnt vmcnt(0)" ::: "memory");
    __syncthreads();

    f32x4 acc0 = {0.f, 0.f, 0.f, 0.f};
    f32x4 acc1 = {0.f, 0.f, 0.f, 0.f};
#pragma unroll
    for (int kk = 0; kk < 16; ++kk) {
      const u32 base = (u32)(kk * 64 + g * 16);
      {
        const int ml = c;
        const u32 off = (u32)(ml * 1024) + (base ^ (u32)((ml & 7) << 4));
        f16x8 a = *(const f16x8*)((const char*)Atile + off);
        acc0 = __builtin_amdgcn_mfma_f32_16x16x32_f16(a, Breg[kk], acc0, 0, 0, 0);
      }
      {
        const int ml = 16 + c;
        const u32 off = (u32)(ml * 1024) + (base ^ (u32)((ml & 7) << 4));
        f16x8 a = *(const f16x8*)((const char*)Atile + off);
        acc1 = __builtin_amdgcn_mfma_f32_16x16x32_f16(a, Breg[kk], acc1, 0, 0, 0);
      }
    }

    const int od0 = mt * 32 + g * 4;
    f32x4 bo0 = *(const f32x4*)(bo + od0);
    f32x4 bo1 = *(const f32x4*)(bo + od0 + 16);
    const float* qp = query + (size_t)row * D_IN + od0;
    f32x4 q0 = *(const f32x4*)(qp);
    f32x4 q1 = *(const f32x4*)(qp + 16);
    f32x4 o0, o1;
#pragma unroll
    for (int i = 0; i < 4; ++i) {
      o0[i] = acc0[i] + bo0[i] + q0[i];
      o1[i] = acc1[i] + bo1[i] + q1[i];
    }
    float* op = out + (size_t)row * D_IN + od0;
    *(f32x4*)(op) = o0;
    *(f32x4*)(op + 16) = o1;
  }
}

extern "C" void kernel_launch(void* const* d_in, const int* in_sizes, int n_in,
                              void* d_out, int out_size, void* d_ws, size_t ws_size,
                              hipStream_t stream) {
  (void)in_sizes; (void)n_in; (void)out_size;
  const float* query = (const float*)d_in[0];
  const float* mkeys = (const float*)d_in[1];
  const float* mvals = (const float*)d_in[2];
  const float* wq    = (const float*)d_in[3];
  const float* bq    = (const float*)d_in[4];
  const float* wo    = (const float*)d_in[5];
  const float* bo    = (const float*)d_in[6];
  float* out = (float*)d_out;

  char* ws = (char*)d_ws;
  f16* keys_h   = (f16*)(ws);                                   //  4 MB
  f16* values_h = (f16*)(ws + (4u << 20));                      //  4 MB
  f16* wqT      = (f16*)(ws + (8u << 20));                      //  1 MB
  f16* woT      = (f16*)(ws + (9u << 20));                      //  1 MB
  f16* q_h      = (f16*)(ws + (10u << 20));                     // 32 MB
  f16* mem_h    = (f16*)(ws + (10u << 20) + (size_t)NROWS * M_DIM * 2);  // 32 MB
  u32* cand     = (u32*)(ws + (10u << 20) + 2ull * (size_t)NROWS * M_DIM * 2); // 2 MB
  const size_t need = (10u << 20) + 2ull * (size_t)NROWS * M_DIM * 2
                    + (size_t)NROWS * 16 * 4;
  if (ws_size < need) return;

  prep_kernel<<<2304, 256, 0, stream>>>(mkeys, mvals, wq, wo, keys_h, values_h, wqT, woT);
  qproj_kernel<<<NROWS / 64, 256, 0, stream>>>(query, wqT, bq, q_h);
  scores_topk_kernel<<<(NROWS / 128) * 2, 512, 0, stream>>>(q_h, keys_h, cand);
  merge_gather_kernel<<<NROWS / 32, 256, 0, stream>>>(cand, values_h, mem_h);
  outproj_kernel<<<(NROWS / 64) * 2, 256, 0, stream>>>(mem_h, woT, bo, query, out);
}

// Round 11
// 348.842 us; speedup vs baseline: 1.4223x; 1.4223x over previous
//
#include <hip/hip_runtime.h>
#include <cstdint>

typedef _Float16 f16;
typedef uint32_t u32;
typedef f16 f16x2 __attribute__((ext_vector_type(2)));
typedef f16 f16x8 __attribute__((ext_vector_type(8)));
typedef float f32x4 __attribute__((ext_vector_type(4)));
typedef u32 u32x4 __attribute__((ext_vector_type(4)));

#define NROWS 32768   // B*S = 8*4096
#define D_IN 1024
#define M_DIM 512
#define NKEYS 4096
#define KTOP 8

__device__ __forceinline__ u32 umax32(u32 a, u32 b) { return a > b ? a : b; }
__device__ __forceinline__ u32 umin32(u32 a, u32 b) { return a < b ? a : b; }

// async global->LDS, 16B per lane. LDS dest is wave-uniform base + lane*16 (HW).
__device__ __forceinline__ void gload_lds16(const void* src, void* dst) {
  __builtin_amdgcn_global_load_lds(
      (const __attribute__((address_space(1))) uint32_t*)src,
      (__attribute__((address_space(3))) uint32_t*)dst, 16, 0, 0);
}

// ---------------------------------------------------------------------------
// prep: fp32->fp16 conversions + weight transposes (LDS-tiled, coalesced)
// ---------------------------------------------------------------------------
__global__ void prep_kernel(const float* __restrict__ keys, const float* __restrict__ values,
                            const float* __restrict__ wq, const float* __restrict__ wo,
                            f16* __restrict__ keys_h, f16* __restrict__ values_h,
                            f16* __restrict__ wqT, f16* __restrict__ woT) {
  const int b = blockIdx.x, t = threadIdx.x;
  if (b < 2048) {
    const float* src = (b < 1024) ? keys : values;
    f16* dst = (b < 1024) ? keys_h : values_h;
    const int bb = b & 1023;
    const size_t base = (size_t)bb * 2048 + (size_t)t * 8;
    f32x4 a = *(const f32x4*)(src + base);
    f32x4 c2 = *(const f32x4*)(src + base + 4);
    f16x8 o;
    o[0] = (f16)a[0]; o[1] = (f16)a[1]; o[2] = (f16)a[2]; o[3] = (f16)a[3];
    o[4] = (f16)c2[0]; o[5] = (f16)c2[1]; o[6] = (f16)c2[2]; o[7] = (f16)c2[3];
    *(f16x8*)(dst + base) = o;
    return;
  }
  __shared__ float lds[64][65];
  if (b < 2176) {
    // wq: [1024 d][512 m] -> wqT [512 m][1024 d]
    const int tb = b - 2048;           // 0..127
    const int td = tb >> 3, tm = tb & 7;
#pragma unroll
    for (int p = 0; p < 16; ++p) {
      const int d_loc = p * 4 + (t >> 6), m_loc = t & 63;
      lds[d_loc][m_loc] = wq[(size_t)(td * 64 + d_loc) * 512 + tm * 64 + m_loc];
    }
    __syncthreads();
#pragma unroll
    for (int p = 0; p < 16; ++p) {
      const int m_loc = p * 4 + (t >> 6), d_loc = t & 63;
      wqT[(size_t)(tm * 64 + m_loc) * 1024 + td * 64 + d_loc] = (f16)lds[d_loc][m_loc];
    }
  } else {
    // wo: [512 m][1024 od] -> woT [1024 od][512 m]
    const int tb = b - 2176;           // 0..127
    const int tmm = tb >> 4, tod = tb & 15;
#pragma unroll
    for (int p = 0; p < 16; ++p) {
      const int m_loc = p * 4 + (t >> 6), od_loc = t & 63;
      lds[m_loc][od_loc] = wo[(size_t)(tmm * 64 + m_loc) * 1024 + tod * 64 + od_loc];
    }
    __syncthreads();
#pragma unroll
    for (int p = 0; p < 16; ++p) {
      const int od_loc = p * 4 + (t >> 6), m_loc = t & 63;
      woT[(size_t)(tod * 64 + od_loc) * 512 + tmm * 64 + m_loc] = (f16)lds[m_loc][od_loc];
    }
  }
}

// ---------------------------------------------------------------------------
// qproj, K-SPLIT wave pairs (new): 512 threads = 4 pairs x 16 rows = 64 rows.
// Wave kp owns dims [kp*512,+512) -> Breg 64 VGPR -> ~90 total -> 4 waves/SIMD
// (vs r2's 128-VGPR 2/SIMD serial structure). Atile 64KB shared by the pair;
// per-mt one f32x4 partial exchange via LDS; epilogue split kp0/kp1 across
// m-col halves. FP order (lo+hi+bq) differs from r2 at ulp level only.
// ---------------------------------------------------------------------------
__global__ __launch_bounds__(512, 4) void qproj_kernel(
    const float* __restrict__ query, const f16* __restrict__ wqT,
    const float* __restrict__ bq, f16* __restrict__ q_out) {
  __shared__ f16 Atile[32 * 1024];     // 64 KB, single-buffered
  __shared__ float xchg[4 * 2 * 256];  // 8 KB: [pair][kp][lane*4]
  const int tid = threadIdx.x;
  const int wave = tid >> 6, lane = tid & 63;
  const int g = lane >> 4, c = lane & 15;
  const int pair = wave >> 1, kp = wave & 1;
  const int rowbase = blockIdx.x * 64 + pair * 16;
  const int row = rowbase + c;

  f16x8 Breg[16];   // query row, dims [kp*512 + kk*32 + g*8, +8)
  {
    const float* qrow = query + (size_t)row * D_IN + kp * 512;
#pragma unroll
    for (int kk = 0; kk < 16; ++kk) {
      f32x4 lo = *(const f32x4*)(qrow + kk * 32 + g * 8);
      f32x4 hi = *(const f32x4*)(qrow + kk * 32 + g * 8 + 4);
      f16x8 v;
      v[0] = (f16)lo[0]; v[1] = (f16)lo[1]; v[2] = (f16)lo[2]; v[3] = (f16)lo[3];
      v[4] = (f16)hi[0]; v[5] = (f16)hi[1]; v[6] = (f16)hi[2]; v[7] = (f16)hi[3];
      Breg[kk] = v;
    }
  }

  float* xsend = xchg + pair * 512 + kp * 256 + lane * 4;
  const float* xrecv = xchg + pair * 512 + (kp ^ 1) * 256 + lane * 4;

  for (int mt = 0; mt < 16; ++mt) {
    __syncthreads();   // prev Atile + xchg consumers done
    // stage 32 m-rows x 2KB, XOR-swizzled (r2 scheme); each wave 4 rows
#pragma unroll
    for (int i2 = 0; i2 < 4; ++i2) {
      const int kr = wave * 4 + i2;
#pragma unroll
      for (int hb = 0; hb < 2; ++hb) {
        const u32 slot = (u32)(hb * 1024 + lane * 16);
        const u32 kb = slot ^ (u32)((kr & 7) << 4);
        const char* src = (const char*)(wqT + (size_t)(mt * 32 + kr) * D_IN) + kb;
        gload_lds16(src, (char*)Atile + kr * 2048 + hb * 1024);
      }
    }
    asm volatile("s_waitcnt vmcnt(0)" ::: "memory");
    __syncthreads();

    f32x4 acc0 = {0.f, 0.f, 0.f, 0.f};
    f32x4 acc1 = {0.f, 0.f, 0.f, 0.f};
#pragma unroll
    for (int kk = 0; kk < 16; ++kk) {
      const u32 base = (u32)(kp * 1024 + kk * 64 + g * 16);
      {
        const int ml = c;
        const u32 off = (u32)(ml * 2048) + (base ^ (u32)((ml & 7) << 4));
        f16x8 a = *(const f16x8*)((const char*)Atile + off);
        acc0 = __builtin_amdgcn_mfma_f32_16x16x32_f16(a, Breg[kk], acc0, 0, 0, 0);
      }
      {
        const int ml = 16 + c;
        const u32 off = (u32)(ml * 2048) + (base ^ (u32)((ml & 7) << 4));
        f16x8 a = *(const f16x8*)((const char*)Atile + off);
        acc1 = __builtin_amdgcn_mfma_f32_16x16x32_f16(a, Breg[kk], acc1, 0, 0, 0);
      }
    }

    // exchange: kp0 sends acc1 (partner finalizes m-cols +16), kp1 sends acc0
    if (kp == 0) { *(f32x4*)xsend = acc1; } else { *(f32x4*)xsend = acc0; }
    __syncthreads();
    {
      f32x4 p = *(const f32x4*)xrecv;
      f32x4 mine = (kp == 0) ? acc0 : acc1;
      const int m0 = mt * 32 + kp * 16 + g * 4;
      f32x4 bqv = *(const f32x4*)(bq + m0);
      f16* qp = q_out + (size_t)row * M_DIM + m0;
      f16x2 o;
      o[0] = (f16)(mine[0] + p[0] + bqv[0]);
      o[1] = (f16)(mine[1] + p[1] + bqv[1]); *(f16x2*)(qp) = o;
      o[0] = (f16)(mine[2] + p[2] + bqv[2]);
      o[1] = (f16)(mine[3] + p[3] + bqv[3]); *(f16x2*)(qp + 2) = o;
    }
  }
}

// ---------------------------------------------------------------------------
// scores+topk (r4 verbatim — best measured, 183.4us): 16x16x32 MFMA,
// 512-thread blocks over a key half, row-major XOR-swizzled LDS, E/O insert
// chains, exact shfl merge across g-lanes.
// ---------------------------------------------------------------------------
__global__ __launch_bounds__(512, 4) void scores_topk_kernel(
    const f16* __restrict__ q, const f16* __restrict__ keys_h,
    u32* __restrict__ cand) {
  __shared__ f16 Ktile[2][32 * 512];   // 2 x 32 KB
  const int tid = threadIdx.x;
  const int wave = tid >> 6, lane = tid & 63;
  const int g = lane >> 4, c = lane & 15;
  const int rb = blockIdx.x >> 1, half = blockIdx.x & 1;
  const int rowbase = rb * 128 + wave * 16;
  const int myrow = rowbase + c;
  const int keybase = half * 2048;

  f16x8 Breg[16];
  {
    const f16* qr = q + (size_t)myrow * M_DIM;
#pragma unroll
    for (int kk = 0; kk < 16; ++kk)
      Breg[kk] = *(const f16x8*)(qr + kk * 32 + g * 8);
  }

  u32 topE[KTOP], topO[KTOP];
#pragma unroll
  for (int j = 0; j < KTOP; ++j) { topE[j] = 0u; topO[j] = 0u; }

  auto stage = [&](int buf, int kt) {
#pragma unroll
    for (int i2 = 0; i2 < 4; ++i2) {
      const int kr = wave * 4 + i2;
      const u32 kb = ((u32)(lane * 16)) ^ ((u32)((kr & 7) << 4));
      const char* src = (const char*)(keys_h + (size_t)(keybase + kt * 32 + kr) * M_DIM) + kb;
      gload_lds16(src, (char*)&Ktile[buf][0] + kr * 1024);
    }
  };

  stage(0, 0);
  asm volatile("s_waitcnt vmcnt(0)" ::: "memory");
  __syncthreads();

  const u32 swz = (u32)((c & 7) << 4);
  const u32 rowb0 = (u32)(c * 1024);
  const u32 rowb1 = (u32)((c + 16) * 1024);   // (c+16)&7 == c&7 -> same swizzle

  for (int kt = 0; kt < 64; ++kt) {
    const int cur = kt & 1;
    if (kt < 63) stage(cur ^ 1, kt + 1);

    f32x4 acc0 = {0.f, 0.f, 0.f, 0.f};
    f32x4 acc1 = {0.f, 0.f, 0.f, 0.f};
    const char* tileb = (const char*)&Ktile[cur][0];
    __builtin_amdgcn_s_setprio(1);
#pragma unroll
    for (int kk = 0; kk < 16; ++kk) {
      const u32 col = ((u32)(kk * 64 + g * 16)) ^ swz;
      f16x8 a0 = *(const f16x8*)(tileb + rowb0 + col);
      f16x8 a1 = *(const f16x8*)(tileb + rowb1 + col);
      acc0 = __builtin_amdgcn_mfma_f32_16x16x32_f16(a0, Breg[kk], acc0, 0, 0, 0);
      acc1 = __builtin_amdgcn_mfma_f32_16x16x32_f16(a1, Breg[kk], acc1, 0, 0, 0);
    }
    __builtin_amdgcn_s_setprio(0);

#pragma unroll
    for (int i = 0; i < 4; ++i) {
      {
        const float s = acc0[i];
        const u32 kidx = (u32)(keybase + kt * 32 + g * 4 + i);
        const int bi = __float_as_int(s);
        const u32 mono = (u32)bi ^ (u32)((bi >> 31) | 0x80000000);   // order-preserving
        u32 x = ((mono + 0x800u) & 0xFFFFF000u) | kidx;              // 20b score + 12b idx
#pragma unroll
        for (int j = 0; j < KTOP; ++j) { const u32 nt = umax32(topE[j], x); x = umin32(topE[j], x); topE[j] = nt; }
      }
      {
        const float s = acc1[i];
        const u32 kidx = (u32)(keybase + kt * 32 + 16 + g * 4 + i);
        const int bi = __float_as_int(s);
        const u32 mono = (u32)bi ^ (u32)((bi >> 31) | 0x80000000);
        u32 x = ((mono + 0x800u) & 0xFFFFF000u) | kidx;
#pragma unroll
        for (int j = 0; j < KTOP; ++j) { const u32 nt = umax32(topO[j], x); x = umin32(topO[j], x); topO[j] = nt; }
      }
    }

    asm volatile("s_waitcnt vmcnt(0)" ::: "memory");
    __syncthreads();
  }

  // merge odd chain into even chain (lane's exact top-8 over its 512 keys)
#pragma unroll
  for (int j = 0; j < KTOP; ++j) {
    u32 x = topO[j];
#pragma unroll
    for (int jj = 0; jj < KTOP; ++jj) { const u32 nt = umax32(topE[jj], x); x = umin32(topE[jj], x); topE[jj] = nt; }
  }
  // merge across the 4 g-lanes sharing row c (disjoint key subsets -> exact)
#pragma unroll
  for (int st = 16; st <= 32; st <<= 1) {
    u32 oth[KTOP];
#pragma unroll
    for (int j = 0; j < KTOP; ++j) oth[j] = (u32)__shfl((int)topE[j], lane ^ st);
#pragma unroll
    for (int j = 0; j < KTOP; ++j) {
      u32 x = oth[j];
#pragma unroll
      for (int jj = 0; jj < KTOP; ++jj) { const u32 nt = umax32(topE[jj], x); x = umin32(topE[jj], x); topE[jj] = nt; }
    }
  }

  if (g == 0) {
    u32* cp = cand + (size_t)myrow * 16 + half * 8;
    u32x4 a, b;
    a.x = topE[0]; a.y = topE[1]; a.z = topE[2]; a.w = topE[3];
    b.x = topE[4]; b.y = topE[5]; b.z = topE[6]; b.w = topE[7];
    *(u32x4*)(cp) = a;
    *(u32x4*)(cp + 4) = b;
  }
}

// ---------------------------------------------------------------------------
// merge halves + softmax + gather. (unchanged)
// ---------------------------------------------------------------------------
__global__ __launch_bounds__(256, 4) void merge_gather_kernel(
    const u32* __restrict__ cand, const f16* __restrict__ values_h,
    f16* __restrict__ mem_out) {
  const int tid = threadIdx.x;
  const int wave = tid >> 6, lane = tid & 63;
  const int rowbase = blockIdx.x * 32 + wave * 8;
  const int myrow = rowbase + (lane & 7);

  const u32* cp = cand + (size_t)myrow * 16;
  u32x4 a0 = *(const u32x4*)(cp);
  u32x4 a1 = *(const u32x4*)(cp + 4);
  u32x4 b0 = *(const u32x4*)(cp + 8);
  u32x4 b1 = *(const u32x4*)(cp + 12);
  u32 top[KTOP] = {a0.x, a0.y, a0.z, a0.w, a1.x, a1.y, a1.z, a1.w};
  u32 ins[KTOP] = {b0.x, b0.y, b0.z, b0.w, b1.x, b1.y, b1.z, b1.w};
#pragma unroll
  for (int j = 0; j < KTOP; ++j) {
    u32 x = ins[j];
#pragma unroll
    for (int jj = 0; jj < KTOP; ++jj) { const u32 nt = umax32(top[jj], x); x = umin32(top[jj], x); top[jj] = nt; }
  }

  float w[KTOP]; u32 idx[KTOP];
  {
    float s[KTOP];
#pragma unroll
    for (int j = 0; j < KTOP; ++j) {
      const u32 mono = top[j] & 0xFFFFF000u;
      const u32 bits = (mono & 0x80000000u) ? (mono ^ 0x80000000u) : ~mono;
      s[j] = __int_as_float(bits);
      idx[j] = top[j] & 0xFFFu;
    }
    const float m0 = s[0];
    float sum = 0.f;
#pragma unroll
    for (int j = 0; j < KTOP; ++j) { w[j] = __expf(s[j] - m0); sum += w[j]; }
    const float inv = 1.f / sum;
#pragma unroll
    for (int j = 0; j < KTOP; ++j) w[j] *= inv;
  }

  for (int r = 0; r < 8; ++r) {
    float acc2[8];
#pragma unroll
    for (int e = 0; e < 8; ++e) acc2[e] = 0.f;
#pragma unroll
    for (int j = 0; j < KTOP; ++j) {
      const u32 ix = (u32)__shfl((int)idx[j], r);
      const float wj = __shfl(w[j], r);
      const f16x8 v = *(const f16x8*)(values_h + (size_t)ix * M_DIM + lane * 8);
#pragma unroll
      for (int e = 0; e < 8; ++e) acc2[e] += wj * (float)v[e];
    }
    f16x8 o;
#pragma unroll
    for (int e = 0; e < 8; ++e) o[e] = (f16)acc2[e];
    *(f16x8*)(mem_out + (size_t)(rowbase + r) * M_DIM + lane * 8) = o;
  }
}

// ---------------------------------------------------------------------------
// outproj (r9 version): r2 math + mt-loop split across grid (4 blocks/CU).
// ---------------------------------------------------------------------------
__global__ __launch_bounds__(256, 4) void outproj_kernel(
    const f16* __restrict__ mem_h, const f16* __restrict__ woT,
    const float* __restrict__ bo, const float* __restrict__ query,
    float* __restrict__ out) {
  __shared__ f16 Atile[32 * 512];   // 32 KB
  const int tid = threadIdx.x;
  const int wave = tid >> 6, lane = tid & 63;
  const int g = lane >> 4, c = lane & 15;
  const int rbk = blockIdx.x >> 1, mh = blockIdx.x & 1;
  const int rowbase = rbk * 64 + wave * 16;
  const int row = rowbase + c;

  f16x8 Breg[16];
  {
    const f16* mr = mem_h + (size_t)row * M_DIM;
#pragma unroll
    for (int kk = 0; kk < 16; ++kk)
      Breg[kk] = *(const f16x8*)(mr + kk * 32 + g * 8);
  }

  for (int mt = mh * 16; mt < mh * 16 + 16; ++mt) {
    __syncthreads();
#pragma unroll
    for (int i2 = 0; i2 < 8; ++i2) {
      const int kr = wave * 8 + i2;
      const u32 kb = ((u32)(lane * 16)) ^ ((u32)((kr & 7) << 4));
      const char* src = (const char*)(woT + (size_t)(mt * 32 + kr) * M_DIM) + kb;
      gload_lds16(src, (char*)Atile + kr * 1024);
    }
    asm volatile("s_waitcnt vmcnt(0)" ::: "memory");
    __syncthreads();

    f32x4 acc0 = {0.f, 0.f, 0.f, 0.f};
    f32x4 acc1 = {0.f, 0.f, 0.f, 0.f};
#pragma unroll
    for (int kk = 0; kk < 16; ++kk) {
      const u32 base = (u32)(kk * 64 + g * 16);
      {
        const int ml = c;
        const u32 off = (u32)(ml * 1024) + (base ^ (u32)((ml & 7) << 4));
        f16x8 a = *(const f16x8*)((const char*)Atile + off);
        acc0 = __builtin_amdgcn_mfma_f32_16x16x32_f16(a, Breg[kk], acc0, 0, 0, 0);
      }
      {
        const int ml = 16 + c;
        const u32 off = (u32)(ml * 1024) + (base ^ (u32)((ml & 7) << 4));
        f16x8 a = *(const f16x8*)((const char*)Atile + off);
        acc1 = __builtin_amdgcn_mfma_f32_16x16x32_f16(a, Breg[kk], acc1, 0, 0, 0);
      }
    }

    const int od0 = mt * 32 + g * 4;
    f32x4 bo0 = *(const f32x4*)(bo + od0);
    f32x4 bo1 = *(const f32x4*)(bo + od0 + 16);
    const float* qp = query + (size_t)row * D_IN + od0;
    f32x4 q0 = *(const f32x4*)(qp);
    f32x4 q1 = *(const f32x4*)(qp + 16);
    f32x4 o0, o1;
#pragma unroll
    for (int i = 0; i < 4; ++i) {
      o0[i] = acc0[i] + bo0[i] + q0[i];
      o1[i] = acc1[i] + bo1[i] + q1[i];
    }
    float* op = out + (size_t)row * D_IN + od0;
    *(f32x4*)(op) = o0;
    *(f32x4*)(op + 16) = o1;
  }
}

extern "C" void kernel_launch(void* const* d_in, const int* in_sizes, int n_in,
                              void* d_out, int out_size, void* d_ws, size_t ws_size,
                              hipStream_t stream) {
  (void)in_sizes; (void)n_in; (void)out_size;
  const float* query = (const float*)d_in[0];
  const float* mkeys = (const float*)d_in[1];
  const float* mvals = (const float*)d_in[2];
  const float* wq    = (const float*)d_in[3];
  const float* bq    = (const float*)d_in[4];
  const float* wo    = (const float*)d_in[5];
  const float* bo    = (const float*)d_in[6];
  float* out = (float*)d_out;

  char* ws = (char*)d_ws;
  f16* keys_h   = (f16*)(ws);                                   //  4 MB
  f16* values_h = (f16*)(ws + (4u << 20));                      //  4 MB
  f16* wqT      = (f16*)(ws + (8u << 20));                      //  1 MB
  f16* woT      = (f16*)(ws + (9u << 20));                      //  1 MB
  f16* q_h      = (f16*)(ws + (10u << 20));                     // 32 MB
  f16* mem_h    = (f16*)(ws + (10u << 20) + (size_t)NROWS * M_DIM * 2);  // 32 MB
  u32* cand     = (u32*)(ws + (10u << 20) + 2ull * (size_t)NROWS * M_DIM * 2); // 2 MB
  const size_t need = (10u << 20) + 2ull * (size_t)NROWS * M_DIM * 2
                    + (size_t)NROWS * 16 * 4;
  if (ws_size < need) return;

  prep_kernel<<<2304, 256, 0, stream>>>(mkeys, mvals, wq, wo, keys_h, values_h, wqT, woT);
  qproj_kernel<<<NROWS / 64, 512, 0, stream>>>(query, wqT, bq, q_h);
  scores_topk_kernel<<<(NROWS / 128) * 2, 512, 0, stream>>>(q_h, keys_h, cand);
  merge_gather_kernel<<<NROWS / 32, 256, 0, stream>>>(cand, values_h, mem_h);
  outproj_kernel<<<(NROWS / 64) * 2, 256, 0, stream>>>(mem_h, woT, bo, query, out);
}

// Round 12
// 345.071 us; speedup vs baseline: 1.4378x; 1.0109x over previous
//
#include <hip/hip_runtime.h>
#include <cstdint>

typedef _Float16 f16;
typedef uint32_t u32;
typedef f16 f16x2 __attribute__((ext_vector_type(2)));
typedef f16 f16x8 __attribute__((ext_vector_type(8)));
typedef float f32x4 __attribute__((ext_vector_type(4)));
typedef u32 u32x4 __attribute__((ext_vector_type(4)));

#define NROWS 32768   // B*S = 8*4096
#define D_IN 1024
#define M_DIM 512
#define NKEYS 4096
#define KTOP 8

__device__ __forceinline__ u32 umax32(u32 a, u32 b) { return a > b ? a : b; }
__device__ __forceinline__ u32 umin32(u32 a, u32 b) { return a < b ? a : b; }

// async global->LDS, 16B per lane. LDS dest is wave-uniform base + lane*16 (HW).
__device__ __forceinline__ void gload_lds16(const void* src, void* dst) {
  __builtin_amdgcn_global_load_lds(
      (const __attribute__((address_space(1))) uint32_t*)src,
      (__attribute__((address_space(3))) uint32_t*)dst, 16, 0, 0);
}

// ---------------------------------------------------------------------------
// prep: fp32->fp16 conversions + weight transposes (LDS-tiled, coalesced)
// ---------------------------------------------------------------------------
__global__ void prep_kernel(const float* __restrict__ keys, const float* __restrict__ values,
                            const float* __restrict__ wq, const float* __restrict__ wo,
                            f16* __restrict__ keys_h, f16* __restrict__ values_h,
                            f16* __restrict__ wqT, f16* __restrict__ woT) {
  const int b = blockIdx.x, t = threadIdx.x;
  if (b < 2048) {
    const float* src = (b < 1024) ? keys : values;
    f16* dst = (b < 1024) ? keys_h : values_h;
    const int bb = b & 1023;
    const size_t base = (size_t)bb * 2048 + (size_t)t * 8;
    f32x4 a = *(const f32x4*)(src + base);
    f32x4 c2 = *(const f32x4*)(src + base + 4);
    f16x8 o;
    o[0] = (f16)a[0]; o[1] = (f16)a[1]; o[2] = (f16)a[2]; o[3] = (f16)a[3];
    o[4] = (f16)c2[0]; o[5] = (f16)c2[1]; o[6] = (f16)c2[2]; o[7] = (f16)c2[3];
    *(f16x8*)(dst + base) = o;
    return;
  }
  __shared__ float lds[64][65];
  if (b < 2176) {
    // wq: [1024 d][512 m] -> wqT [512 m][1024 d]
    const int tb = b - 2048;           // 0..127
    const int td = tb >> 3, tm = tb & 7;
#pragma unroll
    for (int p = 0; p < 16; ++p) {
      const int d_loc = p * 4 + (t >> 6), m_loc = t & 63;
      lds[d_loc][m_loc] = wq[(size_t)(td * 64 + d_loc) * 512 + tm * 64 + m_loc];
    }
    __syncthreads();
#pragma unroll
    for (int p = 0; p < 16; ++p) {
      const int m_loc = p * 4 + (t >> 6), d_loc = t & 63;
      wqT[(size_t)(tm * 64 + m_loc) * 1024 + td * 64 + d_loc] = (f16)lds[d_loc][m_loc];
    }
  } else {
    // wo: [512 m][1024 od] -> woT [1024 od][512 m]
    const int tb = b - 2176;           // 0..127
    const int tmm = tb >> 4, tod = tb & 15;
#pragma unroll
    for (int p = 0; p < 16; ++p) {
      const int m_loc = p * 4 + (t >> 6), od_loc = t & 63;
      lds[m_loc][od_loc] = wo[(size_t)(tmm * 64 + m_loc) * 1024 + tod * 64 + od_loc];
    }
    __syncthreads();
#pragma unroll
    for (int p = 0; p < 16; ++p) {
      const int od_loc = p * 4 + (t >> 6), m_loc = t & 63;
      woT[(size_t)(tod * 64 + od_loc) * 512 + tmm * 64 + m_loc] = (f16)lds[m_loc][od_loc];
    }
  }
}

// ---------------------------------------------------------------------------
// qproj (r2 version, proven): row-major LDS + XOR swizzle, coalesced staging.
// ---------------------------------------------------------------------------
__global__ __launch_bounds__(256, 2) void qproj_kernel(
    const float* __restrict__ query, const f16* __restrict__ wqT,
    const float* __restrict__ bq, f16* __restrict__ q_out) {
  __shared__ f16 Atile[32 * 1024];   // 64 KB
  const int tid = threadIdx.x;
  const int wave = tid >> 6, lane = tid & 63;
  const int g = lane >> 4, c = lane & 15;
  const int rowbase = blockIdx.x * 64 + wave * 16;
  const int row = rowbase + c;

  f16x8 Breg[32];
  {
    const float* qrow = query + (size_t)row * D_IN;
#pragma unroll
    for (int kk = 0; kk < 32; ++kk) {
      f32x4 lo = *(const f32x4*)(qrow + kk * 32 + g * 8);
      f32x4 hi = *(const f32x4*)(qrow + kk * 32 + g * 8 + 4);
      f16x8 v;
      v[0] = (f16)lo[0]; v[1] = (f16)lo[1]; v[2] = (f16)lo[2]; v[3] = (f16)lo[3];
      v[4] = (f16)hi[0]; v[5] = (f16)hi[1]; v[6] = (f16)hi[2]; v[7] = (f16)hi[3];
      Breg[kk] = v;
    }
  }

  for (int mt = 0; mt < 16; ++mt) {
    __syncthreads();
#pragma unroll
    for (int i2 = 0; i2 < 8; ++i2) {
      const int kr = wave * 8 + i2;
#pragma unroll
      for (int hb = 0; hb < 2; ++hb) {
        const u32 slot = (u32)(hb * 1024 + lane * 16);
        const u32 kb = slot ^ (u32)((kr & 7) << 4);
        const char* src = (const char*)(wqT + (size_t)(mt * 32 + kr) * D_IN) + kb;
        gload_lds16(src, (char*)Atile + kr * 2048 + hb * 1024);
      }
    }
    asm volatile("s_waitcnt vmcnt(0)" ::: "memory");
    __syncthreads();

    f32x4 acc0 = {0.f, 0.f, 0.f, 0.f};
    f32x4 acc1 = {0.f, 0.f, 0.f, 0.f};
#pragma unroll
    for (int kk = 0; kk < 32; ++kk) {
      const u32 base = (u32)(kk * 64 + g * 16);
      {
        const int ml = c;
        const u32 off = (u32)(ml * 2048) + (base ^ (u32)((ml & 7) << 4));
        f16x8 a = *(const f16x8*)((const char*)Atile + off);
        acc0 = __builtin_amdgcn_mfma_f32_16x16x32_f16(a, Breg[kk], acc0, 0, 0, 0);
      }
      {
        const int ml = 16 + c;
        const u32 off = (u32)(ml * 2048) + (base ^ (u32)((ml & 7) << 4));
        f16x8 a = *(const f16x8*)((const char*)Atile + off);
        acc1 = __builtin_amdgcn_mfma_f32_16x16x32_f16(a, Breg[kk], acc1, 0, 0, 0);
      }
    }

    f32x4 bq0 = *(const f32x4*)(bq + mt * 32 + g * 4);
    f32x4 bq1 = *(const f32x4*)(bq + mt * 32 + 16 + g * 4);
    f16* qp = q_out + (size_t)row * M_DIM + mt * 32 + g * 4;
    f16x2 p;
    p[0] = (f16)(acc0[0] + bq0[0]); p[1] = (f16)(acc0[1] + bq0[1]); *(f16x2*)(qp + 0) = p;
    p[0] = (f16)(acc0[2] + bq0[2]); p[1] = (f16)(acc0[3] + bq0[3]); *(f16x2*)(qp + 2) = p;
    p[0] = (f16)(acc1[0] + bq1[0]); p[1] = (f16)(acc1[1] + bq1[1]); *(f16x2*)(qp + 16) = p;
    p[0] = (f16)(acc1[2] + bq1[2]); p[1] = (f16)(acc1[3] + bq1[3]); *(f16x2*)(qp + 18) = p;
  }
}

// ---------------------------------------------------------------------------
// scores+topk (r4 verbatim — best measured, 183.4us): 16x16x32 MFMA,
// 512-thread blocks over a key half, row-major XOR-swizzled LDS, E/O insert
// chains, exact shfl merge across g-lanes.
// ---------------------------------------------------------------------------
__global__ __launch_bounds__(512, 4) void scores_topk_kernel(
    const f16* __restrict__ q, const f16* __restrict__ keys_h,
    u32* __restrict__ cand) {
  __shared__ f16 Ktile[2][32 * 512];   // 2 x 32 KB
  const int tid = threadIdx.x;
  const int wave = tid >> 6, lane = tid & 63;
  const int g = lane >> 4, c = lane & 15;
  const int rb = blockIdx.x >> 1, half = blockIdx.x & 1;
  const int rowbase = rb * 128 + wave * 16;
  const int myrow = rowbase + c;
  const int keybase = half * 2048;

  f16x8 Breg[16];
  {
    const f16* qr = q + (size_t)myrow * M_DIM;
#pragma unroll
    for (int kk = 0; kk < 16; ++kk)
      Breg[kk] = *(const f16x8*)(qr + kk * 32 + g * 8);
  }

  u32 topE[KTOP], topO[KTOP];
#pragma unroll
  for (int j = 0; j < KTOP; ++j) { topE[j] = 0u; topO[j] = 0u; }

  auto stage = [&](int buf, int kt) {
#pragma unroll
    for (int i2 = 0; i2 < 4; ++i2) {
      const int kr = wave * 4 + i2;
      const u32 kb = ((u32)(lane * 16)) ^ ((u32)((kr & 7) << 4));
      const char* src = (const char*)(keys_h + (size_t)(keybase + kt * 32 + kr) * M_DIM) + kb;
      gload_lds16(src, (char*)&Ktile[buf][0] + kr * 1024);
    }
  };

  stage(0, 0);
  asm volatile("s_waitcnt vmcnt(0)" ::: "memory");
  __syncthreads();

  const u32 swz = (u32)((c & 7) << 4);
  const u32 rowb0 = (u32)(c * 1024);
  const u32 rowb1 = (u32)((c + 16) * 1024);   // (c+16)&7 == c&7 -> same swizzle

  for (int kt = 0; kt < 64; ++kt) {
    const int cur = kt & 1;
    if (kt < 63) stage(cur ^ 1, kt + 1);

    f32x4 acc0 = {0.f, 0.f, 0.f, 0.f};
    f32x4 acc1 = {0.f, 0.f, 0.f, 0.f};
    const char* tileb = (const char*)&Ktile[cur][0];
    __builtin_amdgcn_s_setprio(1);
#pragma unroll
    for (int kk = 0; kk < 16; ++kk) {
      const u32 col = ((u32)(kk * 64 + g * 16)) ^ swz;
      f16x8 a0 = *(const f16x8*)(tileb + rowb0 + col);
      f16x8 a1 = *(const f16x8*)(tileb + rowb1 + col);
      acc0 = __builtin_amdgcn_mfma_f32_16x16x32_f16(a0, Breg[kk], acc0, 0, 0, 0);
      acc1 = __builtin_amdgcn_mfma_f32_16x16x32_f16(a1, Breg[kk], acc1, 0, 0, 0);
    }
    __builtin_amdgcn_s_setprio(0);

#pragma unroll
    for (int i = 0; i < 4; ++i) {
      {
        const float s = acc0[i];
        const u32 kidx = (u32)(keybase + kt * 32 + g * 4 + i);
        const int bi = __float_as_int(s);
        const u32 mono = (u32)bi ^ (u32)((bi >> 31) | 0x80000000);   // order-preserving
        u32 x = ((mono + 0x800u) & 0xFFFFF000u) | kidx;              // 20b score + 12b idx
#pragma unroll
        for (int j = 0; j < KTOP; ++j) { const u32 nt = umax32(topE[j], x); x = umin32(topE[j], x); topE[j] = nt; }
      }
      {
        const float s = acc1[i];
        const u32 kidx = (u32)(keybase + kt * 32 + 16 + g * 4 + i);
        const int bi = __float_as_int(s);
        const u32 mono = (u32)bi ^ (u32)((bi >> 31) | 0x80000000);
        u32 x = ((mono + 0x800u) & 0xFFFFF000u) | kidx;
#pragma unroll
        for (int j = 0; j < KTOP; ++j) { const u32 nt = umax32(topO[j], x); x = umin32(topO[j], x); topO[j] = nt; }
      }
    }

    asm volatile("s_waitcnt vmcnt(0)" ::: "memory");
    __syncthreads();
  }

  // merge odd chain into even chain (lane's exact top-8 over its 512 keys)
#pragma unroll
  for (int j = 0; j < KTOP; ++j) {
    u32 x = topO[j];
#pragma unroll
    for (int jj = 0; jj < KTOP; ++jj) { const u32 nt = umax32(topE[jj], x); x = umin32(topE[jj], x); topE[jj] = nt; }
  }
  // merge across the 4 g-lanes sharing row c (disjoint key subsets -> exact)
#pragma unroll
  for (int st = 16; st <= 32; st <<= 1) {
    u32 oth[KTOP];
#pragma unroll
    for (int j = 0; j < KTOP; ++j) oth[j] = (u32)__shfl((int)topE[j], lane ^ st);
#pragma unroll
    for (int j = 0; j < KTOP; ++j) {
      u32 x = oth[j];
#pragma unroll
      for (int jj = 0; jj < KTOP; ++jj) { const u32 nt = umax32(topE[jj], x); x = umin32(topE[jj], x); topE[jj] = nt; }
    }
  }

  if (g == 0) {
    u32* cp = cand + (size_t)myrow * 16 + half * 8;
    u32x4 a, b;
    a.x = topE[0]; a.y = topE[1]; a.z = topE[2]; a.w = topE[3];
    b.x = topE[4]; b.y = topE[5]; b.z = topE[6]; b.w = topE[7];
    *(u32x4*)(cp) = a;
    *(u32x4*)(cp + 4) = b;
  }
}

// ---------------------------------------------------------------------------
// merge halves + softmax + gather. (unchanged)
// ---------------------------------------------------------------------------
__global__ __launch_bounds__(256, 4) void merge_gather_kernel(
    const u32* __restrict__ cand, const f16* __restrict__ values_h,
    f16* __restrict__ mem_out) {
  const int tid = threadIdx.x;
  const int wave = tid >> 6, lane = tid & 63;
  const int rowbase = blockIdx.x * 32 + wave * 8;
  const int myrow = rowbase + (lane & 7);

  const u32* cp = cand + (size_t)myrow * 16;
  u32x4 a0 = *(const u32x4*)(cp);
  u32x4 a1 = *(const u32x4*)(cp + 4);
  u32x4 b0 = *(const u32x4*)(cp + 8);
  u32x4 b1 = *(const u32x4*)(cp + 12);
  u32 top[KTOP] = {a0.x, a0.y, a0.z, a0.w, a1.x, a1.y, a1.z, a1.w};
  u32 ins[KTOP] = {b0.x, b0.y, b0.z, b0.w, b1.x, b1.y, b1.z, b1.w};
#pragma unroll
  for (int j = 0; j < KTOP; ++j) {
    u32 x = ins[j];
#pragma unroll
    for (int jj = 0; jj < KTOP; ++jj) { const u32 nt = umax32(top[jj], x); x = umin32(top[jj], x); top[jj] = nt; }
  }

  float w[KTOP]; u32 idx[KTOP];
  {
    float s[KTOP];
#pragma unroll
    for (int j = 0; j < KTOP; ++j) {
      const u32 mono = top[j] & 0xFFFFF000u;
      const u32 bits = (mono & 0x80000000u) ? (mono ^ 0x80000000u) : ~mono;
      s[j] = __int_as_float(bits);
      idx[j] = top[j] & 0xFFFu;
    }
    const float m0 = s[0];
    float sum = 0.f;
#pragma unroll
    for (int j = 0; j < KTOP; ++j) { w[j] = __expf(s[j] - m0); sum += w[j]; }
    const float inv = 1.f / sum;
#pragma unroll
    for (int j = 0; j < KTOP; ++j) w[j] *= inv;
  }

  for (int r = 0; r < 8; ++r) {
    float acc2[8];
#pragma unroll
    for (int e = 0; e < 8; ++e) acc2[e] = 0.f;
#pragma unroll
    for (int j = 0; j < KTOP; ++j) {
      const u32 ix = (u32)__shfl((int)idx[j], r);
      const float wj = __shfl(w[j], r);
      const f16x8 v = *(const f16x8*)(values_h + (size_t)ix * M_DIM + lane * 8);
#pragma unroll
      for (int e = 0; e < 8; ++e) acc2[e] += wj * (float)v[e];
    }
    f16x8 o;
#pragma unroll
    for (int e = 0; e < 8; ++e) o[e] = (f16)acc2[e];
    *(f16x8*)(mem_out + (size_t)(rowbase + r) * M_DIM + lane * 8) = o;
  }
}

// ---------------------------------------------------------------------------
// outproj (r9 version): r2 math + mt-loop split across grid (4 blocks/CU).
// ---------------------------------------------------------------------------
__global__ __launch_bounds__(256, 4) void outproj_kernel(
    const f16* __restrict__ mem_h, const f16* __restrict__ woT,
    const float* __restrict__ bo, const float* __restrict__ query,
    float* __restrict__ out) {
  __shared__ f16 Atile[32 * 512];   // 32 KB
  const int tid = threadIdx.x;
  const int wave = tid >> 6, lane = tid & 63;
  const int g = lane >> 4, c = lane & 15;
  const int rbk = blockIdx.x >> 1, mh = blockIdx.x & 1;
  const int rowbase = rbk * 64 + wave * 16;
  const int row = rowbase + c;

  f16x8 Breg[16];
  {
    const f16* mr = mem_h + (size_t)row * M_DIM;
#pragma unroll
    for (int kk = 0; kk < 16; ++kk)
      Breg[kk] = *(const f16x8*)(mr + kk * 32 + g * 8);
  }

  for (int mt = mh * 16; mt < mh * 16 + 16; ++mt) {
    __syncthreads();
#pragma unroll
    for (int i2 = 0; i2 < 8; ++i2) {
      const int kr = wave * 8 + i2;
      const u32 kb = ((u32)(lane * 16)) ^ ((u32)((kr & 7) << 4));
      const char* src = (const char*)(woT + (size_t)(mt * 32 + kr) * M_DIM) + kb;
      gload_lds16(src, (char*)Atile + kr * 1024);
    }
    asm volatile("s_waitcnt vmcnt(0)" ::: "memory");
    __syncthreads();

    f32x4 acc0 = {0.f, 0.f, 0.f, 0.f};
    f32x4 acc1 = {0.f, 0.f, 0.f, 0.f};
#pragma unroll
    for (int kk = 0; kk < 16; ++kk) {
      const u32 base = (u32)(kk * 64 + g * 16);
      {
        const int ml = c;
        const u32 off = (u32)(ml * 1024) + (base ^ (u32)((ml & 7) << 4));
        f16x8 a = *(const f16x8*)((const char*)Atile + off);
        acc0 = __builtin_amdgcn_mfma_f32_16x16x32_f16(a, Breg[kk], acc0, 0, 0, 0);
      }
      {
        const int ml = 16 + c;
        const u32 off = (u32)(ml * 1024) + (base ^ (u32)((ml & 7) << 4));
        f16x8 a = *(const f16x8*)((const char*)Atile + off);
        acc1 = __builtin_amdgcn_mfma_f32_16x16x32_f16(a, Breg[kk], acc1, 0, 0, 0);
      }
    }

    const int od0 = mt * 32 + g * 4;
    f32x4 bo0 = *(const f32x4*)(bo + od0);
    f32x4 bo1 = *(const f32x4*)(bo + od0 + 16);
    const float* qp = query + (size_t)row * D_IN + od0;
    f32x4 q0 = *(const f32x4*)(qp);
    f32x4 q1 = *(const f32x4*)(qp + 16);
    f32x4 o0, o1;
#pragma unroll
    for (int i = 0; i < 4; ++i) {
      o0[i] = acc0[i] + bo0[i] + q0[i];
      o1[i] = acc1[i] + bo1[i] + q1[i];
    }
    float* op = out + (size_t)row * D_IN + od0;
    *(f32x4*)(op) = o0;
    *(f32x4*)(op + 16) = o1;
  }
}

extern "C" void kernel_launch(void* const* d_in, const int* in_sizes, int n_in,
                              void* d_out, int out_size, void* d_ws, size_t ws_size,
                              hipStream_t stream) {
  (void)in_sizes; (void)n_in; (void)out_size;
  const float* query = (const float*)d_in[0];
  const float* mkeys = (const float*)d_in[1];
  const float* mvals = (const float*)d_in[2];
  const float* wq    = (const float*)d_in[3];
  const float* bq    = (const float*)d_in[4];
  const float* wo    = (const float*)d_in[5];
  const float* bo    = (const float*)d_in[6];
  float* out = (float*)d_out;

  char* ws = (char*)d_ws;
  f16* keys_h   = (f16*)(ws);                                   //  4 MB
  f16* values_h = (f16*)(ws + (4u << 20));                      //  4 MB
  f16* wqT      = (f16*)(ws + (8u << 20));                      //  1 MB
  f16* woT      = (f16*)(ws + (9u << 20));                      //  1 MB
  f16* q_h      = (f16*)(ws + (10u << 20));                     // 32 MB
  f16* mem_h    = (f16*)(ws + (10u << 20) + (size_t)NROWS * M_DIM * 2);  // 32 MB
  u32* cand     = (u32*)(ws + (10u << 20) + 2ull * (size_t)NROWS * M_DIM * 2); // 2 MB
  const size_t need = (10u << 20) + 2ull * (size_t)NROWS * M_DIM * 2
                    + (size_t)NROWS * 16 * 4;
  if (ws_size < need) return;

  prep_kernel<<<2304, 256, 0, stream>>>(mkeys, mvals, wq, wo, keys_h, values_h, wqT, woT);
  qproj_kernel<<<NROWS / 64, 256, 0, stream>>>(query, wqT, bq, q_h);
  scores_topk_kernel<<<(NROWS / 128) * 2, 512, 0, stream>>>(q_h, keys_h, cand);
  merge_gather_kernel<<<NROWS / 32, 256, 0, stream>>>(cand, values_h, mem_h);
  outproj_kernel<<<(NROWS / 64) * 2, 256, 0, stream>>>(mem_h, woT, bo, query, out);
}